// Round 10
// baseline (44.875 us; speedup 1.0000x reference)
//
#include <hip/hip_runtime.h>

#define BB   8
#define RR   128
#define SS   512
#define DD   33
#define EE   128
#define HH   4
#define EKK  32
#define NHH  128
#define HD   (HH*DD)      // 132

// ---- workspace layout (float offsets) ----
#define WS_KT   0                          // B*E*S = 524288 (transposed k-proj)
#define WS_WOT  (BB*EE*SS)                 // HD*NH = 16896
#define WS_QP   (WS_WOT + HD*NHH)          // B*R*E = 131072

#define NB_KP   512
#define NB_QP2  128
#define NB_WOT2 66
#define NB_PREP (NB_KP + NB_QP2 + NB_WOT2)

// ============================================================== K1: prep
__global__ __launch_bounds__(256) void prep_kernel(
    const float* __restrict__ query, const float* __restrict__ key,
    const float* __restrict__ Wq, const float* __restrict__ bq,
    const float* __restrict__ Wk, const float* __restrict__ bk,
    const float* __restrict__ Wo, float* __restrict__ ws)
{
    __shared__ float rows[8 * EE];
    int blk = blockIdx.x, tid = threadIdx.x;

    if (blk < NB_KP) {                 // ---- k proj, 8 rows -> kt[b,e,s]
        int s8 = blk * 8;
#pragma unroll
        for (int i = 0; i < 4; ++i) rows[i * 256 + tid] = key[s8 * EE + i * 256 + tid];
        __syncthreads();
        int g = tid >> 7, e = tid & 127;
        float acc[4];
        float bv = bk[e];
#pragma unroll
        for (int p = 0; p < 4; ++p) acc[p] = bv;
        const float4* W4 = (const float4*)(Wk + e * EE);
        const float4* R4 = (const float4*)rows;
#pragma unroll
        for (int j = 0; j < EE / 4; ++j) {
            float4 w = W4[j];
#pragma unroll
            for (int p = 0; p < 4; ++p) {
                float4 rv = R4[(g * 4 + p) * 32 + j];
                acc[p] += w.x * rv.x + w.y * rv.y + w.z * rv.z + w.w * rv.w;
            }
        }
        int b = s8 / SS, s0 = s8 % SS;
        float4 v; v.x = acc[0]; v.y = acc[1]; v.z = acc[2]; v.w = acc[3];
        *(float4*)(ws + WS_KT + (b * EE + e) * SS + s0 + g * 4) = v;
        return;
    }
    blk -= NB_KP;

    if (blk < NB_QP2) {                // ---- q proj, 8 rows -> qp[b,r,e]
        int br0 = blk * 8;
#pragma unroll
        for (int i = 0; i < 4; ++i) rows[i * 256 + tid] = query[br0 * EE + i * 256 + tid];
        __syncthreads();
        int g = tid >> 7, e = tid & 127;
        float acc[4];
        float bv = bq[e];
#pragma unroll
        for (int p = 0; p < 4; ++p) acc[p] = bv;
        const float4* W4 = (const float4*)(Wq + e * EE);
        const float4* R4 = (const float4*)rows;
#pragma unroll
        for (int j = 0; j < EE / 4; ++j) {
            float4 w = W4[j];
#pragma unroll
            for (int p = 0; p < 4; ++p) {
                float4 rv = R4[(g * 4 + p) * 32 + j];
                acc[p] += w.x * rv.x + w.y * rv.y + w.z * rv.z + w.w * rv.w;
            }
        }
#pragma unroll
        for (int p = 0; p < 4; ++p)
            ws[WS_QP + (br0 + g * 4 + p) * EE + e] = acc[p];
        return;
    }
    blk -= NB_QP2;

    {                                  // ---- Wo transpose -> wot[j][n]
        int gid = blk * 256 + tid;
        if (gid < HD * NHH) {
            int n = gid & 127, j = gid >> 7;
            ws[WS_WOT + gid] = Wo[n * HD + j];
        }
    }
}

// ========== K2: sa + scores + masked softmax + PV + GEMV, 1 r per block
// 1024 blocks x 512 threads; LDS ~23 KB -> 4 blocks/CU, 32 waves/CU
__global__ __launch_bounds__(512, 8) void fused_kernel(
    const float* __restrict__ qp, const float* __restrict__ kt,
    const float* __restrict__ value, const float* __restrict__ maskp,
    const float* __restrict__ tt, const float* __restrict__ qt,
    const float* __restrict__ stridev, const float* __restrict__ Wr,
    const float* __restrict__ brv, const float* __restrict__ wot,
    const float* __restrict__ bo, float* __restrict__ out)
{
    __shared__ float s_q[EE];              // 512 B
    __shared__ float s_tt[SS];             // 2 KB
    __shared__ float s_sa[DD + 3];
    __shared__ float s_e[HH][SS];          // 8 KB
    __shared__ float s_redp[8 * HH * 32];  // 4 KB
    __shared__ float s_redw[8 * HH * 32];  // 4 KB
    __shared__ float s_redv[8 * 32];       // 1 KB
    __shared__ float s_r32p[8 * HH];
    __shared__ float s_r32w[8 * HH];
    __shared__ float s_r32v[8];
    __shared__ float s_x[HD];
    __shared__ float s_part[4][NHH];       // 2 KB

    int blk = blockIdx.x, tid = threadIdx.x;
    int b = blk >> 7, r = blk & 127;

    if (tid < EE) s_q[tid] = qp[(b * RR + r) * EE + tid];
    s_tt[tid] = tt[b * SS + tid];
    if (tid < DD) {                        // sa per-block (33x33 dot, cheap)
        float acc = brv[tid];
#pragma unroll
        for (int j = 0; j < DD; ++j) acc += stridev[j] * Wr[tid * DD + j];
        float sv = 1.0f / (1.0f + __expf(-acc));
        s_sa[tid] = sv;
        if (blk == 0) out[BB * RR * NHH + tid] = sv;   // sa output tail
    }
    __syncthreads();

    // ---- phase A: E[h][s] = exp(score); LDS q via b128 broadcast
    {
        int h = tid >> 7, sq = tid & 127;          // s-quad 4sq..4sq+3
        const float* kb = kt + (b * EE + h * EKK) * SS;
        const float4* q4p = (const float4*)(s_q + h * EKK);
        float4 a = {0.f, 0.f, 0.f, 0.f};
#pragma unroll
        for (int e4 = 0; e4 < 8; ++e4) {
            float4 q4 = q4p[e4];
            float4 k0 = ((const float4*)(kb + (e4 * 4 + 0) * SS))[sq];
            float4 k1 = ((const float4*)(kb + (e4 * 4 + 1) * SS))[sq];
            float4 k2 = ((const float4*)(kb + (e4 * 4 + 2) * SS))[sq];
            float4 k3 = ((const float4*)(kb + (e4 * 4 + 3) * SS))[sq];
            a.x += q4.x * k0.x + q4.y * k1.x + q4.z * k2.x + q4.w * k3.x;
            a.y += q4.x * k0.y + q4.y * k1.y + q4.z * k2.y + q4.w * k3.y;
            a.z += q4.x * k0.z + q4.y * k1.z + q4.z * k2.z + q4.w * k3.z;
            a.w += q4.x * k0.w + q4.y * k1.w + q4.z * k2.w + q4.w * k3.w;
        }
        const float scale = 0.17677669529663687f;  // 1/sqrt(32)
        float4 ev;
        ev.x = __expf(a.x * scale); ev.y = __expf(a.y * scale);
        ev.z = __expf(a.z * scale); ev.w = __expf(a.w * scale);
        ((float4*)s_e[h])[sq] = ev;
    }
    __syncthreads();

    // ---- phase B: lane = (s-parity, d<32)
    int wv = tid >> 6, lane = tid & 63;
    int sp = lane >> 5, d = lane & 31;
    int s0 = wv * 64;
    float qtr = qt[r];

    float ps[HH] = {0,0,0,0}, wsum[HH] = {0,0,0,0};
    float vsum = 0.f;
    {
        float sad = s_sa[d];
        float lo = qtr - sad, hi = qtr + sad;
        const float* vp = value + (size_t)(b * SS + s0 + sp) * DD + d;
        const float* mp = maskp + (size_t)(b * SS + s0 + sp) * DD + d;
#pragma unroll 4
        for (int i = 0; i < 32; ++i) {
            int s = s0 + 2 * i + sp;
            float vv = vp[i * 2 * DD];
            float mv = mp[i * 2 * DD];
            float tv = s_tt[s];
            bool k = (mv != 0.f) & (tv >= lo) & (tv <= hi);
            vsum += vv;
#pragma unroll
            for (int h = 0; h < HH; ++h) {
                float e = s_e[h][s];
                float p = k ? e : 0.f;
                ps[h] += p; wsum[h] += p * vv;
            }
        }
#pragma unroll
        for (int h = 0; h < HH; ++h) {
            ps[h]   += __shfl_xor(ps[h],   32);
            wsum[h] += __shfl_xor(wsum[h], 32);
        }
        vsum += __shfl_xor(vsum, 32);
    }

    // ---- d = 32 tail: lane = th*16 + tj; each tj covers 4 s
    float tps = 0.f, tws = 0.f, tvs = 0.f;
    {
        int th = lane >> 4, tj = lane & 15;
        float sad = s_sa[32];
        float lo = qtr - sad, hi = qtr + sad;
#pragma unroll
        for (int i = 0; i < 4; ++i) {
            int s = s0 + tj * 4 + i;
            float vv = value[(size_t)(b * SS + s) * DD + 32];
            float mv = maskp[(size_t)(b * SS + s) * DD + 32];
            float tv = s_tt[s];
            bool k = (mv != 0.f) & (tv >= lo) & (tv <= hi);
            float e = s_e[th][s];
            float p = k ? e : 0.f;
            tps += p; tws += p * vv; tvs += vv;
        }
#pragma unroll
        for (int off = 1; off < 16; off <<= 1) {
            tps += __shfl_xor(tps, off);
            tws += __shfl_xor(tws, off);
            tvs += __shfl_xor(tvs, off);
        }
    }

    // ---- per-wave partials to LDS (disjoint arrays; no barrier needed yet)
    if (lane < 32) {
#pragma unroll
        for (int h = 0; h < HH; ++h) {
            s_redp[(wv * HH + h) * 32 + d] = ps[h];
            s_redw[(wv * HH + h) * 32 + d] = wsum[h];
        }
        s_redv[wv * 32 + d] = vsum;
    }
    if ((lane & 15) == 0) {
        int th = lane >> 4;
        s_r32p[wv * HH + th] = tps;
        s_r32w[wv * HH + th] = tws;
        if (lane == 0) s_r32v[wv] = tvs;
    }
    __syncthreads();

    // ---- assemble x
    if (tid < 128) {
        int h = tid >> 5, dd = tid & 31;
        float p = 0.f, w = 0.f;
#pragma unroll
        for (int k = 0; k < 8; ++k) {
            p += s_redp[(k * HH + h) * 32 + dd];
            w += s_redw[(k * HH + h) * 32 + dd];
        }
        float xv;
        if (p > 0.f) xv = w / p;
        else {
            float va = 0.f;
#pragma unroll
            for (int k = 0; k < 8; ++k) va += s_redv[k * 32 + dd];
            xv = va * (1.0f / SS);
        }
        s_x[h * DD + dd] = xv;
    } else if (tid < 132) {
        int h = tid - 128;
        float p = 0.f, w = 0.f;
#pragma unroll
        for (int k = 0; k < 8; ++k) {
            p += s_r32p[k * HH + h];
            w += s_r32w[k * HH + h];
        }
        float xv;
        if (p > 0.f) xv = w / p;
        else {
            float va = 0.f;
#pragma unroll
            for (int k = 0; k < 8; ++k) va += s_r32v[k];
            xv = va * (1.0f / SS);
        }
        s_x[h * DD + 32] = xv;
    }
    __syncthreads();

    // ---- phase C: out GEMV, 4-way j-split (4 x 33)
    {
        int g = tid >> 7, n = tid & 127;
        float acc = 0.f;
#pragma unroll
        for (int j = 0; j < 33; ++j)
            acc += s_x[g * 33 + j] * wot[(g * 33 + j) * NHH + n];
        s_part[g][n] = acc;
    }
    __syncthreads();
    if (tid < NHH)
        out[(b * RR + r) * NHH + tid] = bo[tid] + s_part[0][tid] + s_part[1][tid]
                                      + s_part[2][tid] + s_part[3][tid];
}

// ================================================================== launch
extern "C" void kernel_launch(void* const* d_in, const int* in_sizes, int n_in,
                              void* d_out, int out_size, void* d_ws, size_t ws_size,
                              hipStream_t stream) {
    const float* query   = (const float*)d_in[0];
    const float* key     = (const float*)d_in[1];
    const float* value   = (const float*)d_in[2];
    const float* maskp   = (const float*)d_in[3];
    const float* qt      = (const float*)d_in[4];
    const float* tt      = (const float*)d_in[5];
    const float* stridev = (const float*)d_in[6];
    const float* Wq      = (const float*)d_in[7];
    const float* bq      = (const float*)d_in[8];
    const float* Wk      = (const float*)d_in[9];
    const float* bk      = (const float*)d_in[10];
    const float* Wr      = (const float*)d_in[11];
    const float* brv     = (const float*)d_in[12];
    const float* Wo      = (const float*)d_in[13];
    const float* bo      = (const float*)d_in[14];

    float* out = (float*)d_out;               // 131072 out + 33 sa
    float* ws  = (float*)d_ws;

    prep_kernel<<<NB_PREP, 256, 0, stream>>>(
        query, key, Wq, bq, Wk, bk, Wo, ws);
    fused_kernel<<<BB * RR, 512, 0, stream>>>(
        ws + WS_QP, ws + WS_KT, value, maskp, tt, qt,
        stridev, Wr, brv, ws + WS_WOT, bo, out);
}

// Round 11
// 42.991 us; speedup vs baseline: 1.0438x; 1.0438x over previous
//
#include <hip/hip_runtime.h>

#define BB   8
#define RR   128
#define SS   512
#define DD   33
#define EE   128
#define HH   4
#define EKK  32
#define NHH  128
#define HD   (HH*DD)      // 132

// ---- workspace layout (float offsets) ----
#define WS_KT   0                              // B*E*S = 524288
#define WS_WOT  (BB*EE*SS)                     // 16896
#define WS_QP   (WS_WOT + HD*NHH)              // 131072
#define WS_VT   (WS_QP + BB*RR*EE)             // B*D*S = 135168 (value transposed)
#define WS_MB   (WS_VT + BB*DD*SS)             // B*16*36 u32 = 4608 (mask bits)

#define NB_KP   512
#define NB_QP2  128
#define NB_WOT2 66
#define NB_VM   64                             // b x 8 s-strips of 64
#define NB_PREP (NB_KP + NB_QP2 + NB_WOT2 + NB_VM)

// ============================================================== K1: prep
__global__ __launch_bounds__(256) void prep_kernel(
    const float* __restrict__ query, const float* __restrict__ key,
    const float* __restrict__ value, const float* __restrict__ maskp,
    const float* __restrict__ Wq, const float* __restrict__ bq,
    const float* __restrict__ Wk, const float* __restrict__ bk,
    const float* __restrict__ Wo, float* __restrict__ ws)
{
    __shared__ float s_mem[4352];      // union: rows[1024] | tiles[2x2145]
    int blk = blockIdx.x, tid = threadIdx.x;

    if (blk < NB_KP) {                 // ---- k proj, 8 rows -> kt[b,e,s]
        float* rows = s_mem;
        int s8 = blk * 8;
#pragma unroll
        for (int i = 0; i < 4; ++i) rows[i * 256 + tid] = key[s8 * EE + i * 256 + tid];
        __syncthreads();
        int g = tid >> 7, e = tid & 127;
        float acc[4];
        float bv = bk[e];
#pragma unroll
        for (int p = 0; p < 4; ++p) acc[p] = bv;
        const float4* W4 = (const float4*)(Wk + e * EE);
        const float4* R4 = (const float4*)rows;
#pragma unroll
        for (int j = 0; j < EE / 4; ++j) {
            float4 w = W4[j];
#pragma unroll
            for (int p = 0; p < 4; ++p) {
                float4 rv = R4[(g * 4 + p) * 32 + j];
                acc[p] += w.x * rv.x + w.y * rv.y + w.z * rv.z + w.w * rv.w;
            }
        }
        int b = s8 / SS, s0 = s8 % SS;
        float4 v; v.x = acc[0]; v.y = acc[1]; v.z = acc[2]; v.w = acc[3];
        *(float4*)(ws + WS_KT + (b * EE + e) * SS + s0 + g * 4) = v;
        return;
    }
    blk -= NB_KP;

    if (blk < NB_QP2) {                // ---- q proj, 8 rows -> qp[b,r,e]
        float* rows = s_mem;
        int br0 = blk * 8;
#pragma unroll
        for (int i = 0; i < 4; ++i) rows[i * 256 + tid] = query[br0 * EE + i * 256 + tid];
        __syncthreads();
        int g = tid >> 7, e = tid & 127;
        float acc[4];
        float bv = bq[e];
#pragma unroll
        for (int p = 0; p < 4; ++p) acc[p] = bv;
        const float4* W4 = (const float4*)(Wq + e * EE);
        const float4* R4 = (const float4*)rows;
#pragma unroll
        for (int j = 0; j < EE / 4; ++j) {
            float4 w = W4[j];
#pragma unroll
            for (int p = 0; p < 4; ++p) {
                float4 rv = R4[(g * 4 + p) * 32 + j];
                acc[p] += w.x * rv.x + w.y * rv.y + w.z * rv.z + w.w * rv.w;
            }
        }
#pragma unroll
        for (int p = 0; p < 4; ++p)
            ws[WS_QP + (br0 + g * 4 + p) * EE + e] = acc[p];
        return;
    }
    blk -= NB_QP2;

    if (blk < NB_WOT2) {               // ---- Wo transpose -> wot[j][n]
        int gid = blk * 256 + tid;
        if (gid < HD * NHH) {
            int n = gid & 127, j = gid >> 7;
            ws[WS_WOT + gid] = Wo[n * HD + j];
        }
        return;
    }
    blk -= NB_WOT2;

    {   // ---- value transpose + mask bit-pack: b = blk>>3, strip = blk&7
        float* tile_v = s_mem;             // [33][65]
        float* tile_m = s_mem + 2176;      // [33][65]
        int b = blk >> 3, strip = blk & 7;
        int s0 = strip * 64;
        int flat = (b * SS + s0) * DD;     // 2112 consecutive floats
        for (int i = tid; i < 64 * DD; i += 256) {
            int s = i / DD, d = i - s * DD;
            tile_v[d * 65 + s] = value[flat + i];
            tile_m[d * 65 + s] = maskp[flat + i];
        }
        __syncthreads();
        for (int i = tid; i < DD * 64; i += 256) {
            int d = i >> 6, s = i & 63;
            ws[WS_VT + (b * DD + d) * SS + s0 + s] = tile_v[d * 65 + s];
        }
        if (tid < 2 * DD) {                // mask words [b][16][36]
            int wl = tid / DD, d = tid - wl * DD;
            unsigned bits = 0;
#pragma unroll
            for (int j = 0; j < 32; ++j)
                if (tile_m[d * 65 + wl * 32 + j] != 0.f) bits |= (1u << j);
            ((unsigned*)(ws + WS_MB))[(b * 16 + strip * 2 + wl) * 36 + d] = bits;
        }
    }
}

// ================= K2: sa + scores + masked softmax + PV + GEMV, 2 r/block
#define POOL_REDP 0        // [8][2][4][32]
#define POOL_REDW 2048
#define POOL_REDV 4096     // [8][32]
#define POOL_R32P 4352     // [8][2][4]
#define POOL_R32W 4416
#define POOL_R32V 4480     // [8]
#define EIDX(rr,h,s) (((rr)*HH+(h))*SS + (s))

__global__ __launch_bounds__(512) void fused_kernel(
    const float* __restrict__ qp, const float* __restrict__ kt,
    const float* __restrict__ vt, const unsigned* __restrict__ mb,
    const float* __restrict__ tt, const float* __restrict__ qt,
    const float* __restrict__ stridev, const float* __restrict__ Wr,
    const float* __restrict__ brv, const float* __restrict__ wot,
    const float* __restrict__ bo, float* __restrict__ out)
{
    __shared__ float s_q[2][EE];           // 1 KB
    __shared__ float s_tt[SS];             // 2 KB
    __shared__ float s_sa[DD + 3];
    __shared__ unsigned s_mb[16 * 36];     // 2.3 KB, [word][d] padded
    __shared__ float s_pool[4488];         // 17.95 KB (E / reductions union)
    __shared__ float s_x[2][HD];
    __shared__ float s_part[4][NHH];       // 2 KB

    int blk = blockIdx.x, tid = threadIdx.x;
    int b  = blk >> 6;
    int r0 = (blk & 63) * 2;

    if (tid < 256) s_q[tid >> 7][tid & 127] =
        qp[(b * RR + r0 + (tid >> 7)) * EE + (tid & 127)];
    s_tt[tid] = tt[b * SS + tid];
    for (int i = tid; i < 16 * 36; i += 512) s_mb[i] = mb[b * 16 * 36 + i];
    if (tid < DD) {                        // sa per-block (cheap)
        float acc = brv[tid];
#pragma unroll
        for (int j = 0; j < DD; ++j) acc += stridev[j] * Wr[tid * DD + j];
        float sv = 1.0f / (1.0f + __expf(-acc));
        s_sa[tid] = sv;
        if (blk == 0) out[BB * RR * NHH + tid] = sv;   // sa output tail
    }
    __syncthreads();

    // ---- phase A: E[rr][h][s] = exp(score); k loads shared across rr
    {
        int h = tid >> 7, sq = tid & 127;          // s = 4sq..4sq+3
        const float* kb = kt + (b * EE + h * EKK) * SS;
        const float4* q40 = (const float4*)(&s_q[0][h * EKK]);
        const float4* q41 = (const float4*)(&s_q[1][h * EKK]);
        float4 a0 = {0,0,0,0}, a1 = {0,0,0,0};
#pragma unroll
        for (int e4 = 0; e4 < 8; ++e4) {
            float4 qa = q40[e4], qb = q41[e4];
            float4 k0 = ((const float4*)(kb + (e4 * 4 + 0) * SS))[sq];
            float4 k1 = ((const float4*)(kb + (e4 * 4 + 1) * SS))[sq];
            float4 k2 = ((const float4*)(kb + (e4 * 4 + 2) * SS))[sq];
            float4 k3 = ((const float4*)(kb + (e4 * 4 + 3) * SS))[sq];
            a0.x += qa.x*k0.x + qa.y*k1.x + qa.z*k2.x + qa.w*k3.x;
            a0.y += qa.x*k0.y + qa.y*k1.y + qa.z*k2.y + qa.w*k3.y;
            a0.z += qa.x*k0.z + qa.y*k1.z + qa.z*k2.z + qa.w*k3.z;
            a0.w += qa.x*k0.w + qa.y*k1.w + qa.z*k2.w + qa.w*k3.w;
            a1.x += qb.x*k0.x + qb.y*k1.x + qb.z*k2.x + qb.w*k3.x;
            a1.y += qb.x*k0.y + qb.y*k1.y + qb.z*k2.y + qb.w*k3.y;
            a1.z += qb.x*k0.z + qb.y*k1.z + qb.z*k2.z + qb.w*k3.z;
            a1.w += qb.x*k0.w + qb.y*k1.w + qb.z*k2.w + qb.w*k3.w;
        }
        const float scale = 0.17677669529663687f;  // 1/sqrt(32)
        float4 e0, e1;
        e0.x = __expf(a0.x * scale); e0.y = __expf(a0.y * scale);
        e0.z = __expf(a0.z * scale); e0.w = __expf(a0.w * scale);
        e1.x = __expf(a1.x * scale); e1.y = __expf(a1.y * scale);
        e1.z = __expf(a1.z * scale); e1.w = __expf(a1.w * scale);
        *(float4*)&s_pool[EIDX(0, h, 4 * sq)] = e0;
        *(float4*)&s_pool[EIDX(1, h, 4 * sq)] = e1;
    }
    __syncthreads();

    // ---- phase B: lane=(sp,d); 4 consecutive s per lane-iter, b128 E reads
    int wv = tid >> 6, lane = tid & 63;
    int sp = lane >> 5, d = lane & 31;
    int s0 = wv * 64;
    float qtr0 = qt[r0], qtr1 = qt[r0 + 1];

    float ps0[HH] = {0,0,0,0}, ps1[HH] = {0,0,0,0};
    float ws0_[HH] = {0,0,0,0}, ws1_[HH] = {0,0,0,0};
    float vsum = 0.f;
    {
        float sad = s_sa[d];
        float lo0 = qtr0 - sad, hi0 = qtr0 + sad;
        float lo1 = qtr1 - sad, hi1 = qtr1 + sad;
        const float* vrow = vt + (b * DD + d) * SS;
#pragma unroll
        for (int i = 0; i < 8; ++i) {
            int s4 = s0 + i * 8 + sp * 4;
            float4 vv4 = *(const float4*)(vrow + s4);
            float4 t4  = *(const float4*)(s_tt + s4);
            unsigned mw = s_mb[(s4 >> 5) * 36 + d];
            unsigned mnib = (mw >> (s4 & 31)) & 0xFu;
            float4 e0h[HH], e1h[HH];
#pragma unroll
            for (int h = 0; h < HH; ++h) {
                e0h[h] = *(const float4*)&s_pool[EIDX(0, h, s4)];
                e1h[h] = *(const float4*)&s_pool[EIDX(1, h, s4)];
            }
            float tvs4[4] = {t4.x, t4.y, t4.z, t4.w};
            float vvs4[4] = {vv4.x, vv4.y, vv4.z, vv4.w};
#pragma unroll
            for (int u = 0; u < 4; ++u) {
                float tv = tvs4[u], vv = vvs4[u];
                bool mbit = (mnib >> u) & 1u;
                bool k0 = mbit & (tv >= lo0) & (tv <= hi0);
                bool k1 = mbit & (tv >= lo1) & (tv <= hi1);
                vsum += vv;
#pragma unroll
                for (int h = 0; h < HH; ++h) {
                    float e0v = ((const float*)&e0h[h])[u];
                    float e1v = ((const float*)&e1h[h])[u];
                    float p0 = k0 ? e0v : 0.f;
                    float p1 = k1 ? e1v : 0.f;
                    ps0[h] += p0; ws0_[h] = fmaf(p0, vv, ws0_[h]);
                    ps1[h] += p1; ws1_[h] = fmaf(p1, vv, ws1_[h]);
                }
            }
        }
#pragma unroll
        for (int h = 0; h < HH; ++h) {
            ps0[h] += __shfl_xor(ps0[h], 32); ws0_[h] += __shfl_xor(ws0_[h], 32);
            ps1[h] += __shfl_xor(ps1[h], 32); ws1_[h] += __shfl_xor(ws1_[h], 32);
        }
        vsum += __shfl_xor(vsum, 32);
    }

    // ---- d = 32 tail: lane = trr*32 + th*8 + tj; 8 s per lane, b128 reads
    float tps = 0.f, tws = 0.f, tvs = 0.f;
    {
        int trr = lane >> 5, th = (lane >> 3) & 3, tj = lane & 7;
        float sad = s_sa[32];
        float qtrX = trr ? qtr1 : qtr0;
        float lo = qtrX - sad, hi = qtrX + sad;
        int sb = s0 + tj * 8;
        const float* vrow32 = vt + (b * DD + 32) * SS;
        float4 va = *(const float4*)(vrow32 + sb);
        float4 vb = *(const float4*)(vrow32 + sb + 4);
        float4 ta = *(const float4*)(s_tt + sb);
        float4 tb = *(const float4*)(s_tt + sb + 4);
        unsigned mw = s_mb[(sb >> 5) * 36 + 32];
        unsigned mbyte = (mw >> (sb & 31)) & 0xFFu;
        float4 ea = *(const float4*)&s_pool[EIDX(trr, th, sb)];
        float4 eb = *(const float4*)&s_pool[EIDX(trr, th, sb + 4)];
        float tvals[8] = {ta.x,ta.y,ta.z,ta.w,tb.x,tb.y,tb.z,tb.w};
        float vvals[8] = {va.x,va.y,va.z,va.w,vb.x,vb.y,vb.z,vb.w};
        float evals[8] = {ea.x,ea.y,ea.z,ea.w,eb.x,eb.y,eb.z,eb.w};
#pragma unroll
        for (int i = 0; i < 8; ++i) {
            bool k = ((mbyte >> i) & 1u) & (tvals[i] >= lo) & (tvals[i] <= hi);
            float p = k ? evals[i] : 0.f;
            tps += p; tws = fmaf(p, vvals[i], tws); tvs += vvals[i];
        }
#pragma unroll
        for (int off = 1; off < 8; off <<= 1) {
            tps += __shfl_xor(tps, off);
            tws += __shfl_xor(tws, off);
            tvs += __shfl_xor(tvs, off);
        }
    }
    __syncthreads();   // all E reads done; pool reusable

    if (lane < 32) {
#pragma unroll
        for (int h = 0; h < HH; ++h) {
            s_pool[POOL_REDP + ((wv * 2 + 0) * HH + h) * 32 + d] = ps0[h];
            s_pool[POOL_REDP + ((wv * 2 + 1) * HH + h) * 32 + d] = ps1[h];
            s_pool[POOL_REDW + ((wv * 2 + 0) * HH + h) * 32 + d] = ws0_[h];
            s_pool[POOL_REDW + ((wv * 2 + 1) * HH + h) * 32 + d] = ws1_[h];
        }
        s_pool[POOL_REDV + wv * 32 + d] = vsum;
    }
    if ((lane & 7) == 0) {
        int trr = lane >> 5, th = (lane >> 3) & 3;
        s_pool[POOL_R32P + (wv * 2 + trr) * HH + th] = tps;
        s_pool[POOL_R32W + (wv * 2 + trr) * HH + th] = tws;
        if (lane == 0) s_pool[POOL_R32V + wv] = tvs;
    }
    __syncthreads();

    // ---- assemble x
    if (tid < 256) {
        int rr = tid >> 7, hd = tid & 127, h = hd >> 5, dd = hd & 31;
        float p = 0.f, w = 0.f;
#pragma unroll
        for (int k = 0; k < 8; ++k) {
            p += s_pool[POOL_REDP + ((k * 2 + rr) * HH + h) * 32 + dd];
            w += s_pool[POOL_REDW + ((k * 2 + rr) * HH + h) * 32 + dd];
        }
        float xv;
        if (p > 0.f) xv = w / p;
        else {
            float va = 0.f;
#pragma unroll
            for (int k = 0; k < 8; ++k) va += s_pool[POOL_REDV + k * 32 + dd];
            xv = va * (1.0f / SS);
        }
        s_x[rr][h * DD + dd] = xv;
    } else if (tid < 264) {
        int t = tid - 256, rr = t >> 2, h = t & 3;
        float p = 0.f, w = 0.f;
#pragma unroll
        for (int k = 0; k < 8; ++k) {
            p += s_pool[POOL_R32P + (k * 2 + rr) * HH + h];
            w += s_pool[POOL_R32W + (k * 2 + rr) * HH + h];
        }
        float xv;
        if (p > 0.f) xv = w / p;
        else {
            float va = 0.f;
#pragma unroll
            for (int k = 0; k < 8; ++k) va += s_pool[POOL_R32V + k];
            xv = va * (1.0f / SS);
        }
        s_x[rr][h * DD + 32] = xv;
    }
    __syncthreads();

    // ---- phase C: out GEMV for both r (j split 2x66)
    {
        int g2 = tid >> 7;
        int rr = g2 >> 1, jg = g2 & 1;
        int n = tid & 127;
        float acc = 0.f;
#pragma unroll
        for (int j = 0; j < 66; ++j)
            acc += s_x[rr][jg * 66 + j] * wot[(jg * 66 + j) * NHH + n];
        s_part[g2][n] = acc;
    }
    __syncthreads();
    if (tid < 256) {
        int rr = tid >> 7, n = tid & 127;
        out[(b * RR + r0 + rr) * NHH + n] =
            bo[n] + s_part[rr * 2][n] + s_part[rr * 2 + 1][n];
    }
}

// ================================================================== launch
extern "C" void kernel_launch(void* const* d_in, const int* in_sizes, int n_in,
                              void* d_out, int out_size, void* d_ws, size_t ws_size,
                              hipStream_t stream) {
    const float* query   = (const float*)d_in[0];
    const float* key     = (const float*)d_in[1];
    const float* value   = (const float*)d_in[2];
    const float* maskp   = (const float*)d_in[3];
    const float* qt      = (const float*)d_in[4];
    const float* tt      = (const float*)d_in[5];
    const float* stridev = (const float*)d_in[6];
    const float* Wq      = (const float*)d_in[7];
    const float* bq      = (const float*)d_in[8];
    const float* Wk      = (const float*)d_in[9];
    const float* bk      = (const float*)d_in[10];
    const float* Wr      = (const float*)d_in[11];
    const float* brv     = (const float*)d_in[12];
    const float* Wo      = (const float*)d_in[13];
    const float* bo      = (const float*)d_in[14];

    float* out = (float*)d_out;               // 131072 out + 33 sa
    float* ws  = (float*)d_ws;

    prep_kernel<<<NB_PREP, 256, 0, stream>>>(
        query, key, value, maskp, Wq, bq, Wk, bk, Wo, ws);
    fused_kernel<<<BB * 64, 512, 0, stream>>>(
        ws + WS_QP, ws + WS_KT, ws + WS_VT, (const unsigned*)(ws + WS_MB),
        tt, qt, stridev, Wr, brv, ws + WS_WOT, bo, out);
}

// Round 12
// 36.298 us; speedup vs baseline: 1.2363x; 1.1844x over previous
//
#include <hip/hip_runtime.h>

#define BB   8
#define RR   128
#define SS   512
#define DD   33
#define EE   128
#define HH   4
#define EKK  32
#define NHH  128
#define HD   (HH*DD)      // 132

// ---- workspace layout (float offsets) ----
#define WS_KT   0                          // B*E*S = 524288 (transposed k-proj)
#define WS_WOT  (BB*EE*SS)                 // HD*NH = 16896
#define WS_QP   (WS_WOT + HD*NHH)          // B*R*E = 131072

#define NB_KP   512
#define NB_QP2  128
#define NB_WOT2 66
#define NB_PREP (NB_KP + NB_QP2 + NB_WOT2)

// ============================================================== K1: prep
// XCD-aware mapping: batch = blk & 7 so writes land on the XCD (blk % 8)
// that the fused kernel's readers of that batch also occupy.
__global__ __launch_bounds__(256) void prep_kernel(
    const float* __restrict__ query, const float* __restrict__ key,
    const float* __restrict__ Wq, const float* __restrict__ bq,
    const float* __restrict__ Wk, const float* __restrict__ bk,
    const float* __restrict__ Wo, float* __restrict__ ws)
{
    __shared__ float rows[8 * EE];
    int blk = blockIdx.x, tid = threadIdx.x;

    if (blk < NB_KP) {                 // ---- k proj, 8 rows -> kt[b,e,s]
        int bb = blk & 7, j = blk >> 3;        // XCD-aligned: batch = blk%8
        int s8 = bb * SS + j * 8;              // flat row b*S + s0
#pragma unroll
        for (int i = 0; i < 4; ++i) rows[i * 256 + tid] = key[s8 * EE + i * 256 + tid];
        __syncthreads();
        int g = tid >> 7, e = tid & 127;
        float acc[4];
        float bv = bk[e];
#pragma unroll
        for (int p = 0; p < 4; ++p) acc[p] = bv;
        const float4* W4 = (const float4*)(Wk + e * EE);
        const float4* R4 = (const float4*)rows;
#pragma unroll
        for (int j4 = 0; j4 < EE / 4; ++j4) {
            float4 w = W4[j4];
#pragma unroll
            for (int p = 0; p < 4; ++p) {
                float4 rv = R4[(g * 4 + p) * 32 + j4];
                acc[p] += w.x * rv.x + w.y * rv.y + w.z * rv.z + w.w * rv.w;
            }
        }
        int s0 = j * 8;
        float4 v; v.x = acc[0]; v.y = acc[1]; v.z = acc[2]; v.w = acc[3];
        *(float4*)(ws + WS_KT + (bb * EE + e) * SS + s0 + g * 4) = v;
        return;
    }
    blk -= NB_KP;

    if (blk < NB_QP2) {                // ---- q proj, 8 rows -> qp[b,r,e]
        int bb = blk & 7, j = blk >> 3;        // XCD-aligned: batch = blk%8
        int br0 = bb * RR + j * 8;
#pragma unroll
        for (int i = 0; i < 4; ++i) rows[i * 256 + tid] = query[br0 * EE + i * 256 + tid];
        __syncthreads();
        int g = tid >> 7, e = tid & 127;
        float acc[4];
        float bv = bq[e];
#pragma unroll
        for (int p = 0; p < 4; ++p) acc[p] = bv;
        const float4* W4 = (const float4*)(Wq + e * EE);
        const float4* R4 = (const float4*)rows;
#pragma unroll
        for (int j4 = 0; j4 < EE / 4; ++j4) {
            float4 w = W4[j4];
#pragma unroll
            for (int p = 0; p < 4; ++p) {
                float4 rv = R4[(g * 4 + p) * 32 + j4];
                acc[p] += w.x * rv.x + w.y * rv.y + w.z * rv.z + w.w * rv.w;
            }
        }
#pragma unroll
        for (int p = 0; p < 4; ++p)
            ws[WS_QP + (br0 + g * 4 + p) * EE + e] = acc[p];
        return;
    }
    blk -= NB_QP2;

    {                                  // ---- Wo transpose -> wot[j][n]
        int gid = blk * 256 + tid;
        if (gid < HD * NHH) {
            int n = gid & 127, j = gid >> 7;
            ws[WS_WOT + gid] = Wo[n * HD + j];
        }
    }
}

// ================= K2: sa + scores + masked softmax + PV + GEMV, 2 r/block
// XCD-aware: batch = blk & 7 -> all 64 blocks of batch b on XCD b; kt[b]
// (256 KB) becomes L2-local for all 64 re-reads.
#define POOL_REDP 0        // [8][2][4][32]
#define POOL_REDW 2048
#define POOL_REDV 4096     // [8][32]
#define POOL_R32P 4352     // [8][2][4]
#define POOL_R32W 4416
#define POOL_R32V 4480     // [8]
#define EIDX(rr,h,s) (((rr)*HH+(h))*SS + (s))

__global__ __launch_bounds__(512) void fused_kernel(
    const float* __restrict__ qp, const float* __restrict__ kt,
    const float* __restrict__ value, const float* __restrict__ maskp,
    const float* __restrict__ tt, const float* __restrict__ qt,
    const float* __restrict__ stridev, const float* __restrict__ Wr,
    const float* __restrict__ brv, const float* __restrict__ wot,
    const float* __restrict__ bo, float* __restrict__ out)
{
    __shared__ float s_q[2][EE];
    __shared__ float s_tt[SS];
    __shared__ float s_sa[DD + 3];
    __shared__ float s_pool[4488];
    __shared__ float s_x[2][HD];
    __shared__ float s_part[4][NHH];

    int blk = blockIdx.x, tid = threadIdx.x;
    int b  = blk & 7;                      // XCD-aligned batch
    int r0 = (blk >> 3) * 2;

    if (tid < 256) s_q[tid >> 7][tid & 127] =
        qp[(b * RR + r0 + (tid >> 7)) * EE + (tid & 127)];
    s_tt[tid] = tt[b * SS + tid];
    if (tid < DD) {                        // sa per-block (cheap)
        float acc = brv[tid];
#pragma unroll
        for (int j = 0; j < DD; ++j) acc += stridev[j] * Wr[tid * DD + j];
        float sv = 1.0f / (1.0f + __expf(-acc));
        s_sa[tid] = sv;
        if (blk == 0) out[BB * RR * NHH + tid] = sv;   // sa output tail
    }
    __syncthreads();

    // ---- phase A: E[rr][h][s] = exp(score); float4 k loads shared by rr
    {
        int h = tid >> 7, sq = tid & 127;
        const float* kb = kt + (b * EE + h * EKK) * SS;
        float4 a0 = {0,0,0,0}, a1 = {0,0,0,0};
#pragma unroll
        for (int e = 0; e < EKK; ++e) {
            float4 kv = ((const float4*)(kb + e * SS))[sq];
            float q0 = s_q[0][h * EKK + e];
            float q1 = s_q[1][h * EKK + e];
            a0.x += q0 * kv.x; a0.y += q0 * kv.y; a0.z += q0 * kv.z; a0.w += q0 * kv.w;
            a1.x += q1 * kv.x; a1.y += q1 * kv.y; a1.z += q1 * kv.z; a1.w += q1 * kv.w;
        }
        const float scale = 0.17677669529663687f;  // 1/sqrt(32)
        float4 e0, e1;
        e0.x = __expf(a0.x * scale); e0.y = __expf(a0.y * scale);
        e0.z = __expf(a0.z * scale); e0.w = __expf(a0.w * scale);
        e1.x = __expf(a1.x * scale); e1.y = __expf(a1.y * scale);
        e1.z = __expf(a1.z * scale); e1.w = __expf(a1.w * scale);
        ((float4*)&s_pool[EIDX(0, h, 0)])[sq] = e0;
        ((float4*)&s_pool[EIDX(1, h, 0)])[sq] = e1;
    }
    __syncthreads();

    // ---- phase B: lane = (s-parity, d<32)
    int wv = tid >> 6, lane = tid & 63;
    int sp = lane >> 5, d = lane & 31;
    int s0 = wv * 64;
    float qtr0 = qt[r0], qtr1 = qt[r0 + 1];

    float ps0[HH] = {0,0,0,0}, ps1[HH] = {0,0,0,0};
    float ws0_[HH] = {0,0,0,0}, ws1_[HH] = {0,0,0,0};
    float vsum = 0.f;
    {
        float sad = s_sa[d];
        float lo0 = qtr0 - sad, hi0 = qtr0 + sad;
        float lo1 = qtr1 - sad, hi1 = qtr1 + sad;
        const float* vp = value + (size_t)(b * SS + s0 + sp) * DD + d;
        const float* mp = maskp + (size_t)(b * SS + s0 + sp) * DD + d;
#pragma unroll 4
        for (int i = 0; i < 32; ++i) {
            int s = s0 + 2 * i + sp;
            float vv = vp[i * 2 * DD];
            float mv = mp[i * 2 * DD];
            float tv = s_tt[s];
            bool mb = (mv != 0.f);
            bool k0 = mb & (tv >= lo0) & (tv <= hi0);
            bool k1 = mb & (tv >= lo1) & (tv <= hi1);
            vsum += vv;
#pragma unroll
            for (int h = 0; h < HH; ++h) {
                float e0 = s_pool[EIDX(0, h, s)];
                float e1 = s_pool[EIDX(1, h, s)];
                float p0 = k0 ? e0 : 0.f;
                float p1 = k1 ? e1 : 0.f;
                ps0[h] += p0; ws0_[h] += p0 * vv;
                ps1[h] += p1; ws1_[h] += p1 * vv;
            }
        }
#pragma unroll
        for (int h = 0; h < HH; ++h) {
            ps0[h] += __shfl_xor(ps0[h], 32); ws0_[h] += __shfl_xor(ws0_[h], 32);
            ps1[h] += __shfl_xor(ps1[h], 32); ws1_[h] += __shfl_xor(ws1_[h], 32);
        }
        vsum += __shfl_xor(vsum, 32);
    }

    // ---- d = 32 tail: lane = trr*32 + th*8 + tj, each tj covers 8 s
    float tps = 0.f, tws = 0.f, tvs = 0.f;
    {
        int trr = lane >> 5, th = (lane >> 3) & 3, tj = lane & 7;
        float sad = s_sa[32];
        float qtrX = trr ? qtr1 : qtr0;
        float lo = qtrX - sad, hi = qtrX + sad;
#pragma unroll
        for (int i = 0; i < 8; ++i) {
            int s = s0 + tj * 8 + i;
            float vv = value[(size_t)(b * SS + s) * DD + 32];
            float mv = maskp[(size_t)(b * SS + s) * DD + 32];
            float tv = s_tt[s];
            bool k = (mv != 0.f) & (tv >= lo) & (tv <= hi);
            float e = s_pool[EIDX(trr, th, s)];
            float p = k ? e : 0.f;
            tps += p; tws += p * vv; tvs += vv;
        }
#pragma unroll
        for (int off = 1; off < 8; off <<= 1) {
            tps += __shfl_xor(tps, off);
            tws += __shfl_xor(tws, off);
            tvs += __shfl_xor(tvs, off);
        }
    }
    __syncthreads();   // all E reads done; pool reusable

    if (lane < 32) {
#pragma unroll
        for (int h = 0; h < HH; ++h) {
            s_pool[POOL_REDP + ((wv * 2 + 0) * HH + h) * 32 + d] = ps0[h];
            s_pool[POOL_REDP + ((wv * 2 + 1) * HH + h) * 32 + d] = ps1[h];
            s_pool[POOL_REDW + ((wv * 2 + 0) * HH + h) * 32 + d] = ws0_[h];
            s_pool[POOL_REDW + ((wv * 2 + 1) * HH + h) * 32 + d] = ws1_[h];
        }
        s_pool[POOL_REDV + wv * 32 + d] = vsum;
    }
    if ((lane & 7) == 0) {
        int trr = lane >> 5, th = (lane >> 3) & 3;
        s_pool[POOL_R32P + (wv * 2 + trr) * HH + th] = tps;
        s_pool[POOL_R32W + (wv * 2 + trr) * HH + th] = tws;
        if (lane == 0) s_pool[POOL_R32V + wv] = tvs;
    }
    __syncthreads();

    // ---- assemble x
    if (tid < 256) {
        int rr = tid >> 7, hd = tid & 127, h = hd >> 5, dd = hd & 31;
        float p = 0.f, w = 0.f;
#pragma unroll
        for (int k = 0; k < 8; ++k) {
            p += s_pool[POOL_REDP + ((k * 2 + rr) * HH + h) * 32 + dd];
            w += s_pool[POOL_REDW + ((k * 2 + rr) * HH + h) * 32 + dd];
        }
        float xv;
        if (p > 0.f) xv = w / p;
        else {
            float va = 0.f;
#pragma unroll
            for (int k = 0; k < 8; ++k) va += s_pool[POOL_REDV + k * 32 + dd];
            xv = va * (1.0f / SS);
        }
        s_x[rr][h * DD + dd] = xv;
    } else if (tid < 264) {
        int t = tid - 256, rr = t >> 2, h = t & 3;
        float p = 0.f, w = 0.f;
#pragma unroll
        for (int k = 0; k < 8; ++k) {
            p += s_pool[POOL_R32P + (k * 2 + rr) * HH + h];
            w += s_pool[POOL_R32W + (k * 2 + rr) * HH + h];
        }
        float xv;
        if (p > 0.f) xv = w / p;
        else {
            float va = 0.f;
#pragma unroll
            for (int k = 0; k < 8; ++k) va += s_pool[POOL_R32V + k];
            xv = va * (1.0f / SS);
        }
        s_x[rr][h * DD + 32] = xv;
    }
    __syncthreads();

    // ---- phase C: out GEMV for both r (j split 2x66)
    {
        int g2 = tid >> 7;
        int rr = g2 >> 1, jg = g2 & 1;
        int n = tid & 127;
        float acc = 0.f;
#pragma unroll
        for (int j = 0; j < 66; ++j)
            acc += s_x[rr][jg * 66 + j] * wot[(jg * 66 + j) * NHH + n];
        s_part[g2][n] = acc;
    }
    __syncthreads();
    if (tid < 256) {
        int rr = tid >> 7, n = tid & 127;
        out[(b * RR + r0 + rr) * NHH + n] =
            bo[n] + s_part[rr * 2][n] + s_part[rr * 2 + 1][n];
    }
}

// ================================================================== launch
extern "C" void kernel_launch(void* const* d_in, const int* in_sizes, int n_in,
                              void* d_out, int out_size, void* d_ws, size_t ws_size,
                              hipStream_t stream) {
    const float* query   = (const float*)d_in[0];
    const float* key     = (const float*)d_in[1];
    const float* value   = (const float*)d_in[2];
    const float* maskp   = (const float*)d_in[3];
    const float* qt      = (const float*)d_in[4];
    const float* tt      = (const float*)d_in[5];
    const float* stridev = (const float*)d_in[6];
    const float* Wq      = (const float*)d_in[7];
    const float* bq      = (const float*)d_in[8];
    const float* Wk      = (const float*)d_in[9];
    const float* bk      = (const float*)d_in[10];
    const float* Wr      = (const float*)d_in[11];
    const float* brv     = (const float*)d_in[12];
    const float* Wo      = (const float*)d_in[13];
    const float* bo      = (const float*)d_in[14];

    float* out = (float*)d_out;               // 131072 out + 33 sa
    float* ws  = (float*)d_ws;

    prep_kernel<<<NB_PREP, 256, 0, stream>>>(
        query, key, Wq, bq, Wk, bk, Wo, ws);
    fused_kernel<<<BB * 64, 512, 0, stream>>>(
        ws + WS_QP, ws + WS_KT, value, maskp, tt, qt,
        stridev, Wr, brv, ws + WS_WOT, bo, out);
}

// Round 13
// 35.023 us; speedup vs baseline: 1.2813x; 1.0364x over previous
//
#include <hip/hip_runtime.h>

#define BB   8
#define RR   128
#define SS   512
#define DD   33
#define EE   128
#define HH   4
#define EKK  32
#define NHH  128
#define HD   (HH*DD)      // 132

// ---- workspace layout (float offsets) ----
#define WS_KT   0                          // B*E*S = 524288 (transposed k-proj)
#define WS_WOT  (BB*EE*SS)                 // HD*NH = 16896
#define WS_QP   (WS_WOT + HD*NHH)          // B*R*E = 131072

#define NB_KP   512
#define NB_QP2  128
#define NB_WOT2 66
#define NB_PREP (NB_KP + NB_QP2 + NB_WOT2)

// ============================================================== K1: prep
// XCD-aware mapping: batch = blk & 7 so writes land on the XCD that the
// fused kernel's readers of that batch also occupy.
__global__ __launch_bounds__(256) void prep_kernel(
    const float* __restrict__ query, const float* __restrict__ key,
    const float* __restrict__ Wq, const float* __restrict__ bq,
    const float* __restrict__ Wk, const float* __restrict__ bk,
    const float* __restrict__ Wo, float* __restrict__ ws)
{
    __shared__ float rows[8 * EE];
    int blk = blockIdx.x, tid = threadIdx.x;

    if (blk < NB_KP) {                 // ---- k proj, 8 rows -> kt[b,e,s]
        int bb = blk & 7, j = blk >> 3;
        int s8 = bb * SS + j * 8;
#pragma unroll
        for (int i = 0; i < 4; ++i) rows[i * 256 + tid] = key[s8 * EE + i * 256 + tid];
        __syncthreads();
        int g = tid >> 7, e = tid & 127;
        float acc[4];
        float bv = bk[e];
#pragma unroll
        for (int p = 0; p < 4; ++p) acc[p] = bv;
        const float4* W4 = (const float4*)(Wk + e * EE);
        const float4* R4 = (const float4*)rows;
#pragma unroll
        for (int j4 = 0; j4 < EE / 4; ++j4) {
            float4 w = W4[j4];
#pragma unroll
            for (int p = 0; p < 4; ++p) {
                float4 rv = R4[(g * 4 + p) * 32 + j4];
                acc[p] += w.x * rv.x + w.y * rv.y + w.z * rv.z + w.w * rv.w;
            }
        }
        int s0 = j * 8;
        float4 v; v.x = acc[0]; v.y = acc[1]; v.z = acc[2]; v.w = acc[3];
        *(float4*)(ws + WS_KT + (bb * EE + e) * SS + s0 + g * 4) = v;
        return;
    }
    blk -= NB_KP;

    if (blk < NB_QP2) {                // ---- q proj, 8 rows -> qp[b,r,e]
        int bb = blk & 7, j = blk >> 3;
        int br0 = bb * RR + j * 8;
#pragma unroll
        for (int i = 0; i < 4; ++i) rows[i * 256 + tid] = query[br0 * EE + i * 256 + tid];
        __syncthreads();
        int g = tid >> 7, e = tid & 127;
        float acc[4];
        float bv = bq[e];
#pragma unroll
        for (int p = 0; p < 4; ++p) acc[p] = bv;
        const float4* W4 = (const float4*)(Wq + e * EE);
        const float4* R4 = (const float4*)rows;
#pragma unroll
        for (int j4 = 0; j4 < EE / 4; ++j4) {
            float4 w = W4[j4];
#pragma unroll
            for (int p = 0; p < 4; ++p) {
                float4 rv = R4[(g * 4 + p) * 32 + j4];
                acc[p] += w.x * rv.x + w.y * rv.y + w.z * rv.z + w.w * rv.w;
            }
        }
#pragma unroll
        for (int p = 0; p < 4; ++p)
            ws[WS_QP + (br0 + g * 4 + p) * EE + e] = acc[p];
        return;
    }
    blk -= NB_QP2;

    {                                  // ---- Wo transpose -> wot[j][n]
        int gid = blk * 256 + tid;
        if (gid < HD * NHH) {
            int n = gid & 127, j = gid >> 7;
            ws[WS_WOT + gid] = Wo[n * HD + j];
        }
    }
}

// ================= K2: sa + scores + masked softmax + PV + GEMV, 2 r/block
// XCD-aware: batch = blk & 7. Phase B: consecutive-s lanes -> b128 E reads.
#define POOL_REDP 0        // [8][2][4][32]
#define POOL_REDW 2048
#define POOL_REDV 4096     // [8][32]
#define POOL_R32P 4352     // [8][2][4]
#define POOL_R32W 4416
#define POOL_R32V 4480     // [8]
#define EIDX(rr,h,s) (((rr)*HH+(h))*SS + (s))

__global__ __launch_bounds__(512) void fused_kernel(
    const float* __restrict__ qp, const float* __restrict__ kt,
    const float* __restrict__ value, const float* __restrict__ maskp,
    const float* __restrict__ tt, const float* __restrict__ qt,
    const float* __restrict__ stridev, const float* __restrict__ Wr,
    const float* __restrict__ brv, const float* __restrict__ wot,
    const float* __restrict__ bo, float* __restrict__ out)
{
    __shared__ float s_q[2][EE];
    __shared__ float s_tt[SS];
    __shared__ float s_sa[DD + 3];
    __shared__ float s_pool[4488];
    __shared__ float s_x[2][HD];
    __shared__ float s_part[4][NHH];

    int blk = blockIdx.x, tid = threadIdx.x;
    int b  = blk & 7;                      // XCD-aligned batch
    int r0 = (blk >> 3) * 2;

    if (tid < 256) s_q[tid >> 7][tid & 127] =
        qp[(b * RR + r0 + (tid >> 7)) * EE + (tid & 127)];
    s_tt[tid] = tt[b * SS + tid];
    if (tid < DD) {                        // sa per-block (cheap)
        float acc = brv[tid];
#pragma unroll
        for (int j = 0; j < DD; ++j) acc += stridev[j] * Wr[tid * DD + j];
        float sv = 1.0f / (1.0f + __expf(-acc));
        s_sa[tid] = sv;
        if (blk == 0) out[BB * RR * NHH + tid] = sv;   // sa output tail
    }
    __syncthreads();

    // ---- phase A: E[rr][h][s] = exp(score); float4 k loads shared by rr
    {
        int h = tid >> 7, sq = tid & 127;
        const float* kb = kt + (b * EE + h * EKK) * SS;
        float4 a0 = {0,0,0,0}, a1 = {0,0,0,0};
#pragma unroll
        for (int e = 0; e < EKK; ++e) {
            float4 kv = ((const float4*)(kb + e * SS))[sq];
            float q0 = s_q[0][h * EKK + e];
            float q1 = s_q[1][h * EKK + e];
            a0.x += q0 * kv.x; a0.y += q0 * kv.y; a0.z += q0 * kv.z; a0.w += q0 * kv.w;
            a1.x += q1 * kv.x; a1.y += q1 * kv.y; a1.z += q1 * kv.z; a1.w += q1 * kv.w;
        }
        const float scale = 0.17677669529663687f;  // 1/sqrt(32)
        float4 e0, e1;
        e0.x = __expf(a0.x * scale); e0.y = __expf(a0.y * scale);
        e0.z = __expf(a0.z * scale); e0.w = __expf(a0.w * scale);
        e1.x = __expf(a1.x * scale); e1.y = __expf(a1.y * scale);
        e1.z = __expf(a1.z * scale); e1.w = __expf(a1.w * scale);
        ((float4*)&s_pool[EIDX(0, h, 0)])[sq] = e0;
        ((float4*)&s_pool[EIDX(1, h, 0)])[sq] = e1;
    }
    __syncthreads();

    // ---- phase B: lane = (s-half, d<32); 32 CONSECUTIVE s per lane,
    //      E read as b128 (4 s per LDS instr, wave-broadcast addresses)
    int wv = tid >> 6, lane = tid & 63;
    int sp = lane >> 5, d = lane & 31;
    int wbase = wv * 64;
    int sb0 = wbase + sp * 32;             // this lane's 32-s strip
    float qtr0 = qt[r0], qtr1 = qt[r0 + 1];

    float ps0[HH] = {0,0,0,0}, ps1[HH] = {0,0,0,0};
    float ws0_[HH] = {0,0,0,0}, ws1_[HH] = {0,0,0,0};
    float vsum = 0.f;
    {
        float sad = s_sa[d];
        float lo0 = qtr0 - sad, hi0 = qtr0 + sad;
        float lo1 = qtr1 - sad, hi1 = qtr1 + sad;
        const float* vp = value + (size_t)(b * SS + sb0) * DD + d;
        const float* mp = maskp + (size_t)(b * SS + sb0) * DD + d;
#pragma unroll
        for (int i4 = 0; i4 < 8; ++i4) {
            int s4 = sb0 + i4 * 4;
            float4 t4 = *(const float4*)&s_tt[s4];
            float4 e0q[HH], e1q[HH];
#pragma unroll
            for (int h = 0; h < HH; ++h) {
                e0q[h] = *(const float4*)&s_pool[EIDX(0, h, s4)];
                e1q[h] = *(const float4*)&s_pool[EIDX(1, h, s4)];
            }
            float tvs[4] = {t4.x, t4.y, t4.z, t4.w};
#pragma unroll
            for (int u = 0; u < 4; ++u) {
                int i = i4 * 4 + u;
                float vv = vp[i * DD];
                float mv = mp[i * DD];
                float tv = tvs[u];
                bool mb = (mv != 0.f);
                bool k0 = mb & (tv >= lo0) & (tv <= hi0);
                bool k1 = mb & (tv >= lo1) & (tv <= hi1);
                vsum += vv;
                float g0  = k0 ? 1.f : 0.f, gv0 = k0 ? vv : 0.f;
                float g1  = k1 ? 1.f : 0.f, gv1 = k1 ? vv : 0.f;
#pragma unroll
                for (int h = 0; h < HH; ++h) {
                    float e0v = ((const float*)&e0q[h])[u];
                    float e1v = ((const float*)&e1q[h])[u];
                    ps0[h]  = fmaf(e0v, g0,  ps0[h]);
                    ws0_[h] = fmaf(e0v, gv0, ws0_[h]);
                    ps1[h]  = fmaf(e1v, g1,  ps1[h]);
                    ws1_[h] = fmaf(e1v, gv1, ws1_[h]);
                }
            }
        }
#pragma unroll
        for (int h = 0; h < HH; ++h) {
            ps0[h] += __shfl_xor(ps0[h], 32); ws0_[h] += __shfl_xor(ws0_[h], 32);
            ps1[h] += __shfl_xor(ps1[h], 32); ws1_[h] += __shfl_xor(ws1_[h], 32);
        }
        vsum += __shfl_xor(vsum, 32);
    }

    // ---- d = 32 tail: lane = trr*32 + th*8 + tj; 8 consecutive s, b128 E
    float tps = 0.f, tws = 0.f, tvs = 0.f;
    {
        int trr = lane >> 5, th = (lane >> 3) & 3, tj = lane & 7;
        float sad = s_sa[32];
        float qtrX = trr ? qtr1 : qtr0;
        float lo = qtrX - sad, hi = qtrX + sad;
        int sb = wbase + tj * 8;
        float4 ea = *(const float4*)&s_pool[EIDX(trr, th, sb)];
        float4 eb = *(const float4*)&s_pool[EIDX(trr, th, sb + 4)];
        float4 ta = *(const float4*)&s_tt[sb];
        float4 tb = *(const float4*)&s_tt[sb + 4];
        float evals[8] = {ea.x,ea.y,ea.z,ea.w,eb.x,eb.y,eb.z,eb.w};
        float tvals[8] = {ta.x,ta.y,ta.z,ta.w,tb.x,tb.y,tb.z,tb.w};
#pragma unroll
        for (int i = 0; i < 8; ++i) {
            int s = sb + i;
            float vv = value[(size_t)(b * SS + s) * DD + 32];
            float mv = maskp[(size_t)(b * SS + s) * DD + 32];
            bool k = (mv != 0.f) & (tvals[i] >= lo) & (tvals[i] <= hi);
            float p = k ? evals[i] : 0.f;
            tps += p; tws = fmaf(p, vv, tws); tvs += vv;
        }
#pragma unroll
        for (int off = 1; off < 8; off <<= 1) {
            tps += __shfl_xor(tps, off);
            tws += __shfl_xor(tws, off);
            tvs += __shfl_xor(tvs, off);
        }
    }
    __syncthreads();   // all E reads done; pool reusable

    if (lane < 32) {
#pragma unroll
        for (int h = 0; h < HH; ++h) {
            s_pool[POOL_REDP + ((wv * 2 + 0) * HH + h) * 32 + d] = ps0[h];
            s_pool[POOL_REDP + ((wv * 2 + 1) * HH + h) * 32 + d] = ps1[h];
            s_pool[POOL_REDW + ((wv * 2 + 0) * HH + h) * 32 + d] = ws0_[h];
            s_pool[POOL_REDW + ((wv * 2 + 1) * HH + h) * 32 + d] = ws1_[h];
        }
        s_pool[POOL_REDV + wv * 32 + d] = vsum;
    }
    if ((lane & 7) == 0) {
        int trr = lane >> 5, th = (lane >> 3) & 3;
        s_pool[POOL_R32P + (wv * 2 + trr) * HH + th] = tps;
        s_pool[POOL_R32W + (wv * 2 + trr) * HH + th] = tws;
        if (lane == 0) s_pool[POOL_R32V + wv] = tvs;
    }
    __syncthreads();

    // ---- assemble x
    if (tid < 256) {
        int rr = tid >> 7, hd = tid & 127, h = hd >> 5, dd = hd & 31;
        float p = 0.f, w = 0.f;
#pragma unroll
        for (int k = 0; k < 8; ++k) {
            p += s_pool[POOL_REDP + ((k * 2 + rr) * HH + h) * 32 + dd];
            w += s_pool[POOL_REDW + ((k * 2 + rr) * HH + h) * 32 + dd];
        }
        float xv;
        if (p > 0.f) xv = w / p;
        else {
            float va = 0.f;
#pragma unroll
            for (int k = 0; k < 8; ++k) va += s_pool[POOL_REDV + k * 32 + dd];
            xv = va * (1.0f / SS);
        }
        s_x[rr][h * DD + dd] = xv;
    } else if (tid < 264) {
        int t = tid - 256, rr = t >> 2, h = t & 3;
        float p = 0.f, w = 0.f;
#pragma unroll
        for (int k = 0; k < 8; ++k) {
            p += s_pool[POOL_R32P + (k * 2 + rr) * HH + h];
            w += s_pool[POOL_R32W + (k * 2 + rr) * HH + h];
        }
        float xv;
        if (p > 0.f) xv = w / p;
        else {
            float va = 0.f;
#pragma unroll
            for (int k = 0; k < 8; ++k) va += s_pool[POOL_R32V + k];
            xv = va * (1.0f / SS);
        }
        s_x[rr][h * DD + 32] = xv;
    }
    __syncthreads();

    // ---- phase C: out GEMV for both r (j split 2x66)
    {
        int g2 = tid >> 7;
        int rr = g2 >> 1, jg = g2 & 1;
        int n = tid & 127;
        float acc = 0.f;
#pragma unroll
        for (int j = 0; j < 66; ++j)
            acc += s_x[rr][jg * 66 + j] * wot[(jg * 66 + j) * NHH + n];
        s_part[g2][n] = acc;
    }
    __syncthreads();
    if (tid < 256) {
        int rr = tid >> 7, n = tid & 127;
        out[(b * RR + r0 + rr) * NHH + n] =
            bo[n] + s_part[rr * 2][n] + s_part[rr * 2 + 1][n];
    }
}

// ================================================================== launch
extern "C" void kernel_launch(void* const* d_in, const int* in_sizes, int n_in,
                              void* d_out, int out_size, void* d_ws, size_t ws_size,
                              hipStream_t stream) {
    const float* query   = (const float*)d_in[0];
    const float* key     = (const float*)d_in[1];
    const float* value   = (const float*)d_in[2];
    const float* maskp   = (const float*)d_in[3];
    const float* qt      = (const float*)d_in[4];
    const float* tt      = (const float*)d_in[5];
    const float* stridev = (const float*)d_in[6];
    const float* Wq      = (const float*)d_in[7];
    const float* bq      = (const float*)d_in[8];
    const float* Wk      = (const float*)d_in[9];
    const float* bk      = (const float*)d_in[10];
    const float* Wr      = (const float*)d_in[11];
    const float* brv     = (const float*)d_in[12];
    const float* Wo      = (const float*)d_in[13];
    const float* bo      = (const float*)d_in[14];

    float* out = (float*)d_out;               // 131072 out + 33 sa
    float* ws  = (float*)d_ws;

    prep_kernel<<<NB_PREP, 256, 0, stream>>>(
        query, key, Wq, bq, Wk, bk, Wo, ws);
    fused_kernel<<<BB * 64, 512, 0, stream>>>(
        ws + WS_QP, ws + WS_KT, value, maskp, tt, qt,
        stridev, Wr, brv, ws + WS_WOT, bo, out);
}